// Round 12
// baseline (231.027 us; speedup 1.0000x reference)
//
#include <hip/hip_runtime.h>
#include <cfloat>
#include <cstdint>

#define B_  64
#define T_  1024
#define D_  128
#define NE  512            // clip limit; emb has NE+1 = 513 rows
#define P_  (B_*T_)        // 65536 positions

// d_out flat offsets (float32), in reference return order
#define O_KH   0
#define O_ENC  (P_*D_)             // 8388608
#define O_V    (O_ENC + P_)        // 8454144
#define O_LH   (O_V + 1)           // 8454145
#define O_LN   (O_LH + P_)         // 8519681
#define O_EM   (O_LN + P_)         // 8585217
#define O_LED  (O_EM + 1)          // 8585218

typedef __attribute__((ext_vector_type(8))) short bf16x8;
typedef __attribute__((ext_vector_type(4))) float floatx4;
typedef unsigned long long u64;

// hi = truncate-to-bf16(x), lo = truncate-to-bf16(x - hi); pack 8 floats ->
// two uint4 (8 bf16 each, k-ascending little-endian)
__device__ __forceinline__ void pack8(const float4& a, const float4& b,
                                      uint4& h, uint4& l)
{
    float v[8] = {a.x,a.y,a.z,a.w,b.x,b.y,b.z,b.w};
    unsigned hw[4], lw[4];
    #pragma unroll
    for (int e = 0; e < 4; e++) {
        const unsigned ua = __float_as_uint(v[2*e]);
        const unsigned ub = __float_as_uint(v[2*e+1]);
        const float fa = __uint_as_float(ua & 0xffff0000u);
        const float fb = __uint_as_float(ub & 0xffff0000u);
        const unsigned da = __float_as_uint(v[2*e]   - fa);
        const unsigned db = __float_as_uint(v[2*e+1] - fb);
        hw[e] = (ub & 0xffff0000u) | (ua >> 16);
        lw[e] = (db & 0xffff0000u) | (da >> 16);
    }
    h = make_uint4(hw[0],hw[1],hw[2],hw[3]);
    l = make_uint4(lw[0],lw[1],lw[2],lw[3]);
}

__device__ __forceinline__ u64 shflx64(u64 v, int d)
{
    const int lo = __shfl_xor((int)(unsigned)(v & 0xffffffffULL), d);
    const int hi = __shfl_xor((int)(unsigned)(v >> 32), d);
    return ((u64)(unsigned)hi << 32) | (unsigned)lo;
}

// monotone float->uint map (strictly increasing) — EXACT, no quantization
__device__ __forceinline__ unsigned sortkey(float f)
{
    const unsigned b = __float_as_uint(f);
    return b ^ (unsigned)(((int)b >> 31) | (int)0x80000000);
}

// ---------------------------------------------------------------------------
// kFG: emb-only pre-conversion. Grid 32 x 64. Block 0 zeroes the kD
// completion counter (stream-ordered before kD1 -> safe).
// ---------------------------------------------------------------------------
__global__ __launch_bounds__(64) void kFG(const float* __restrict__ emb,
                                          unsigned short* __restrict__ ehi,
                                          unsigned short* __restrict__ elo,
                                          float* __restrict__ sq,
                                          unsigned* __restrict__ cnt)
{
    if (blockIdx.x == 0 && threadIdx.x == 0) *cnt = 0u;
    const int t = blockIdx.x * 64 + threadIdx.x;   // 0..2047
    const int n = t >> 2, kst = t & 3;
    const float4* src = (const float4*)(emb + (size_t)n * D_ + kst * 32);
    float ss = 0.f;
    #pragma unroll
    for (int g = 0; g < 4; g++) {
        const float4 a = src[2*g], b = src[2*g+1];
        ss += a.x*a.x + a.y*a.y + a.z*a.z + a.w*a.w
            + b.x*b.x + b.y*b.y + b.z*b.z + b.w*b.w;
        uint4 h, l;
        pack8(a, b, h, l);
        const int f = ((n >> 4) * 4 + kst) * 4 + g;
        *(uint4*)(ehi + (size_t)f*128 + (size_t)(n & 15)*8) = h;
        *(uint4*)(elo + (size_t)f*128 + (size_t)(n & 15)*8) = l;
    }
    ss += __shfl_xor(ss, 1);
    ss += __shfl_xor(ss, 2);
    if (kst == 0) sq[n] = ss;
}

// ---------------------------------------------------------------------------
// kA: transposed MFMA GEMM (M = n, N = p). One block = 512 threads = 8 waves
// = all 8 chunks of one 32-row p-half-tile; grid 2048; ks loaded+packed ONCE
// through LDS (XOR swizzle); in-block bit63 (R11).
// R12: occupancy play — kA is stage-latency-bound (8 serial block-batches/CU
// at 2 resident blocks; 700 GB/s << BW ceiling; MFMA busy only ~10us).
// Single-buffered A-frags (R7's A-dbuf cost 32 VGPR and measured ~0) bring
// unified regs back to ~84 <= 512/6, so __launch_bounds__(512, 6) requests
// 6 waves/SIMD = 3 blocks/CU (75% ceiling vs 50%) -> stage phases of 3
// blocks overlap. MFMA operand values/order unchanged -> bit-identical.
// NO cross-block fencing (R6: 2048 device-scope fences = 16x regression).
// ---------------------------------------------------------------------------
__global__ __launch_bounds__(512, 6) void kA(const float* __restrict__ ks,
                                          const float* __restrict__ sq,
                                          const unsigned short* __restrict__ ehi,
                                          const unsigned short* __restrict__ elo,
                                          u64* __restrict__ bits,
                                          unsigned* __restrict__ mins,
                                          unsigned short* __restrict__ mini16)
{
    __shared__ unsigned short Bh[32*128];   // 8 KB, [row][col] bf16, swizzled
    __shared__ unsigned short Bl[32*128];   // 8 KB
    __shared__ float S00x[8][2][16];        // 1 KB: S[0][0] per (wave, j, m)

    const int tid  = threadIdx.x;
    const int lane = tid & 63;
    const int wv   = tid >> 6;                // 0..7
    const int m    = lane & 15;               // p within 16-tile
    const int q    = lane >> 4;               // quad
    const int bid  = blockIdx.x;
    const int h    = bid >> 10;               // p-half 0/1
    const int pt   = bid & 1023;
    const int p0   = pt * 64 + h * 32;        // first p of this block
    const int ch   = wv;                      // chunk 0..7
    const int nb   = ch * 64;

    // ---- cooperative stage: 512 threads x 32 B -> 16 KB bf16 hi/lo ----
    {
        const int srow = tid >> 4;            // 0..31
        const int scg  = tid & 15;            // 8-col group
        const float4* sp = (const float4*)(ks + ((size_t)p0 + srow)*D_ + scg*8);
        uint4 hh, ll;
        pack8(sp[0], sp[1], hh, ll);
        const int cb = (srow*256 + scg*16) ^ ((srow & 7) << 4);
        *(uint4*)((char*)Bh + cb) = hh;
        *(uint4*)((char*)Bl + cb) = ll;
    }
    __syncthreads();

    floatx4 acc[4][2];
    #pragma unroll
    for (int i = 0; i < 4; i++)
        #pragma unroll
        for (int j = 0; j < 2; j++)
            #pragma unroll
            for (int r = 0; r < 4; r++) acc[i][j][r] = 0.f;

    bf16x8 ah[4], al[4], bh[2], bl[2];

    auto loadA = [&](int kst) {
        #pragma unroll
        for (int i = 0; i < 4; i++) {
            const int off = (((ch*4 + i) * 4 + kst) * 4 + q) * 128 + m*8;
            ah[i] = *(const bf16x8*)(ehi + off);
            al[i] = *(const bf16x8*)(elo + off);
        }
    };
    auto loadB = [&](int kst) {
        #pragma unroll
        for (int j = 0; j < 2; j++) {
            const int row = j*16 + m;
            const int cb = (row*256 + kst*64 + q*16) ^ ((row & 7) << 4);
            bh[j] = *(const bf16x8*)((const char*)Bh + cb);
            bl[j] = *(const bf16x8*)((const char*)Bl + cb);
        }
    };
    auto mfma3 = [&]() {
        __builtin_amdgcn_s_setprio(1);
        #pragma unroll
        for (int i = 0; i < 4; i++)
            #pragma unroll
            for (int j = 0; j < 2; j++)
                acc[i][j] = __builtin_amdgcn_mfma_f32_16x16x32_bf16(ah[i], bh[j], acc[i][j], 0, 0, 0);
        #pragma unroll
        for (int i = 0; i < 4; i++)
            #pragma unroll
            for (int j = 0; j < 2; j++)
                acc[i][j] = __builtin_amdgcn_mfma_f32_16x16x32_bf16(ah[i], bl[j], acc[i][j], 0, 0, 0);
        #pragma unroll
        for (int i = 0; i < 4; i++)
            #pragma unroll
            for (int j = 0; j < 2; j++)
                acc[i][j] = __builtin_amdgcn_mfma_f32_16x16x32_bf16(al[i], bh[j], acc[i][j], 0, 0, 0);
        __builtin_amdgcn_s_setprio(0);
    };

    #pragma unroll
    for (int kst = 0; kst < 3; kst++) {
        loadA(kst);
        loadB(kst);
        mfma3();
    }
    loadA(3);
    loadB(3);
    // prefetch epilogue sq under the last MFMA cluster
    float sa[4][4];
    #pragma unroll
    for (int i = 0; i < 4; i++) {
        const float4 s4 = *(const float4*)(sq + nb + i*16 + q*4);
        sa[i][0]=s4.x; sa[i][1]=s4.y; sa[i][2]=s4.z; sa[i][3]=s4.w;
    }
    mfma3();

    // ---- publish S[0][0] per (wave, j, m) for the in-block bit63 patch.
    // Same expression the main loop computes on the q==0 lane -> bitwise
    // identical to the value previously stored in sfirst. ----
    if (q == 0) {
        S00x[wv][0][m] = fmaf(-2.f, acc[0][0][0], sa[0][0]);
        S00x[wv][1][m] = fmaf(-2.f, acc[0][1][0], sa[0][0]);
    }
    __syncthreads();
    const int wnx = (wv < 7) ? wv + 1 : 7;           // clamped (unused at ch==7)

    // ---- epilogue (register-local; bit63 fully resolved here) ----
    #pragma unroll
    for (int j = 0; j < 2; j++) {
        float S[4][4];
        #pragma unroll
        for (int i = 0; i < 4; i++)
            #pragma unroll
            for (int r = 0; r < 4; r++)
                S[i][r] = fmaf(-2.f, acc[i][j][r], sa[i][r]);

        // neighbor S at quad/tile boundaries
        float nq[4], ni[4];
        #pragma unroll
        for (int i = 0; i < 4; i++) nq[i] = __shfl_down(S[i][0], 16);
        #pragma unroll
        for (int i = 0; i < 3; i++) ni[i] = __shfl(S[i+1][0], m);
        ni[3] = 0.f;

        u64 w = 0;
        #pragma unroll
        for (int i = 0; i < 4; i++) {
            #pragma unroll
            for (int r = 0; r < 3; r++)
                w |= (u64)(S[i][r] <= S[i][r+1]) << (16*i + 4*q + r);
            if (!(i == 3 && q == 3)) {
                const float nxt = (q < 3) ? nq[i] : ni[i];
                w |= (u64)(S[i][3] <= nxt) << (16*i + 4*q + 3);
            }
        }
        // bit63: chunk-boundary "stay" bit. ch==7 -> n=511 clip (always
        // stay); else compare this chunk's last S with next chunk's first S
        // (value read from LDS; bitwise equal to the old sfirst round-trip).
        if (q == 3) {
            const u64 b63 = (ch == 7) ? 1ULL
                          : (u64)(S[3][3] <= S00x[wnx][j][m]);
            w |= b63 << 63;
        }
        w |= shflx64(w, 16);
        w |= shflx64(w, 32);

        // chunk argmin, EXACT (first-index tie-break)
        float mv = S[0][0]; int mi_ = nb + q*4;
        #pragma unroll
        for (int i = 0; i < 4; i++)
            #pragma unroll
            for (int r = 0; r < 4; r++) {
                if (i == 0 && r == 0) continue;
                const int nid = nb + 16*i + 4*q + r;
                if (S[i][r] < mv) { mv = S[i][r]; mi_ = nid; }
            }
        #pragma unroll
        for (int d = 16; d <= 32; d <<= 1) {
            const float v2 = __shfl_xor(mv, d);
            const int   i2 = __shfl_xor(mi_, d);
            if (v2 < mv || (v2 == mv && i2 < mi_)) { mv = v2; mi_ = i2; }
        }

        const size_t pg = (size_t)(p0 + j*16 + m);
        if (q == 0) {
            bits  [pg*8 + ch] = w;
            mins  [pg*8 + ch] = sortkey(mv);
            mini16[pg*8 + ch] = (unsigned short)mi_;
        }
    }
}

// ---------------------------------------------------------------------------
// kB: one wave per b. Windows carry ONLY the 8 bits words (64 B/t; bit63
// arrives pre-resolved from kA). Scalarized named registers (R10: struct
// buffers were demoted to scratch), 4 rotating windows = 3-deep prefetch,
// loads issued before ind0. Same scan arithmetic, window order 0..15 ->
// bit-identical outputs.
// ---------------------------------------------------------------------------
#define KB_DECL(S) \
    u64 W0##S,W1##S,W2##S,W3##S,W4##S,W5##S,W6##S,W7##S;

#define KB_LOAD(S, T0)                                                      \
    {                                                                       \
        const int t_ = (T0) + lane;                                         \
        if (t_ < T_) {                                                      \
            const ulonglong2* bp_ = (const ulonglong2*)(bits + (p0 + t_)*8);\
            const ulonglong2 b01_ = bp_[0], b23_ = bp_[1];                  \
            const ulonglong2 b45_ = bp_[2], b67_ = bp_[3];                  \
            W0##S=b01_.x; W1##S=b01_.y; W2##S=b23_.x; W3##S=b23_.y;         \
            W4##S=b45_.x; W5##S=b45_.y; W6##S=b67_.x; W7##S=b67_.y;         \
        } else {                                                            \
            W0##S=~0ULL; W1##S=~0ULL; W2##S=~0ULL; W3##S=~0ULL;             \
            W4##S=~0ULL; W5##S=~0ULL; W6##S=~0ULL; W7##S=~0ULL;             \
        }                                                                   \
    }

#define KB_SCAN(S, T0)                                                      \
    {                                                                       \
        const int wsel_ = cur >> 6;                                         \
        const int off0_ = cur & 63;                                         \
        u64 a_ = W0##S;                                                     \
        a_ = (wsel_ == 1) ? W1##S : a_;                                     \
        a_ = (wsel_ == 2) ? W2##S : a_;                                     \
        a_ = (wsel_ == 3) ? W3##S : a_;                                     \
        a_ = (wsel_ == 4) ? W4##S : a_;                                     \
        a_ = (wsel_ == 5) ? W5##S : a_;                                     \
        a_ = (wsel_ == 6) ? W6##S : a_;                                     \
        a_ = (wsel_ == 7) ? W7##S : a_;                                     \
        u64 bn_ = ~0ULL;                                                    \
        bn_ = (wsel_ == 0) ? W1##S : bn_;                                   \
        bn_ = (wsel_ == 1) ? W2##S : bn_;                                   \
        bn_ = (wsel_ == 2) ? W3##S : bn_;                                   \
        bn_ = (wsel_ == 3) ? W4##S : bn_;                                   \
        bn_ = (wsel_ == 4) ? W5##S : bn_;                                   \
        bn_ = (wsel_ == 5) ? W6##S : bn_;                                   \
        bn_ = (wsel_ == 6) ? W7##S : bn_;                                   \
        const u64 u_ = (off0_ == 0) ? a_                                    \
                     : ((a_ >> off0_) | (bn_ << (64 - off0_)));             \
        const unsigned ulo_ = (unsigned)u_;                                 \
        const unsigned uhi_ = (unsigned)(u_ >> 32);                         \
        int doff_ = 0;                                                      \
        int myenc_ = cur;                                                   \
        _Pragma("unroll")                                                   \
        for (int j_ = 0; j_ < 64; j_++) {                                   \
            const unsigned slo_ = (unsigned)__builtin_amdgcn_readlane((int)ulo_, j_); \
            const unsigned shi_ = (unsigned)__builtin_amdgcn_readlane((int)uhi_, j_); \
            const u64 word_ = ((u64)shi_ << 32) | slo_;                     \
            const int bit_ = (int)((word_ >> doff_) & 1ULL);                \
            doff_ += 1 - bit_;                                              \
            if (lane == j_) myenc_ = cur + doff_;                           \
        }                                                                   \
        cur += doff_;                                                       \
        const int t_ = (T0) + lane;                                         \
        if (t_ < T_) {                                                      \
            enci[p0 + t_] = myenc_;                                         \
            out[O_ENC + p0 + t_] = (float)myenc_;                           \
        }                                                                   \
    }

__global__ __launch_bounds__(64) void kB(const float* __restrict__ ks,
                                         const float* __restrict__ emb,
                                         const unsigned char* __restrict__ mask,
                                         const u64* __restrict__ bits,
                                         const unsigned* __restrict__ mins,
                                         const unsigned short* __restrict__ mini16,
                                         int* __restrict__ enci,
                                         float* __restrict__ out)
{
    const int b    = blockIdx.x;
    const int lane = threadIdx.x;
    const size_t p0 = (size_t)b * T_;

    KB_DECL(A)
    KB_DECL(B)
    KB_DECL(C)
    KB_DECL(D)

    // windows 0..3 in flight BEFORE ind0 (independent of it) — ind0's
    // emb/ks loads + reduce cover their cross-XCD latency.
    KB_LOAD(A, 1)
    KB_LOAD(B, 65)
    KB_LOAD(C, 129)
    KB_LOAD(D, 193)

    // ind0: S[512] exact + 8 exact chunk keys
    const float2 e = ((const float2*)(emb + (size_t)512*D_))[lane];
    const float2 k = ((const float2*)(ks  + p0*D_))[lane];
    float s5 = e.x*(e.x - 2.f*k.x) + e.y*(e.y - 2.f*k.y);
    #pragma unroll
    for (int m = 32; m >= 1; m >>= 1) s5 += __shfl_xor(s5, m);

    u64 kk = ~0ULL;
    if (lane < 8)       kk = ((u64)mins[p0*8 + lane] << 32) | (u64)mini16[p0*8 + lane];
    else if (lane == 8) kk = ((u64)sortkey(s5) << 32) | 512ULL;
    #pragma unroll
    for (int d = 1; d <= 8; d <<= 1) {
        const u64 o = shflx64(kk, d);
        kk = (o < kk) ? o : kk;
    }
    const int mi = __shfl((int)(unsigned)(kk & 0xffffffffULL), 0);
    int cur = (mi < NE) ? mi : NE - 1;
    if (mask[b]) cur = 0;
    if (lane == 0) { enci[p0] = cur; out[O_ENC + p0] = (float)cur; }

    #pragma unroll 1
    for (int wp = 0; wp < 16; wp += 4) {
        const int t0 = 1 + wp*64;
        KB_SCAN(A, t0)
        if (wp + 4 < 16) KB_LOAD(A, t0 + 256)
        KB_SCAN(B, t0 + 64)
        if (wp + 5 < 16) KB_LOAD(B, t0 + 320)
        KB_SCAN(C, t0 + 128)
        if (wp + 6 < 16) KB_LOAD(C, t0 + 384)
        KB_SCAN(D, t0 + 192)
        if (wp + 7 < 16) KB_LOAD(D, t0 + 448)
    }
}

// ---------------------------------------------------------------------------
// kC: one wave per position, quad-split. Quad q computes one dot:
// q0: S[eh], q1: S[en], q2: S[512], q3: ||ks||^2. Global argmin via EXACT
// u64 keys. pm is SELECTED (pm=ph / pn / p5) when mi hits a special case —
// bitwise-guaranteed equality regardless of codegen/contraction. Recompute
// only for genuinely distinct mi (real gap -> rounding-safe).
// ---------------------------------------------------------------------------
__global__ __launch_bounds__(256) void kC(const float* __restrict__ ks,
                                          const float* __restrict__ emb,
                                          const int* __restrict__ enci,
                                          const unsigned* __restrict__ mins,
                                          const unsigned short* __restrict__ mini16,
                                          float* __restrict__ out,
                                          float* __restrict__ energy)
{
    const int lane = threadIdx.x & 63;
    const size_t p = (size_t)blockIdx.x * 4 + (threadIdx.x >> 6);
    const int q  = lane >> 4;
    const int qm = lane & 15;

    const int eh = enci[p];
    const int en = (eh + 1 < NE) ? eh + 1 : NE - 1;
    const int row = (q == 0) ? eh : ((q == 1) ? en : 512);

    const float4* ksp = (const float4*)(ks + p*D_);
    const float4 k1 = ksp[qm*2], k2 = ksp[qm*2 + 1];
    const float4* ep = (const float4*)(emb + (size_t)row*D_);
    const float4 e1 = ep[qm*2], e2 = ep[qm*2 + 1];

    float d;
    if (q == 3) {
        d = k1.x*k1.x + k1.y*k1.y + k1.z*k1.z + k1.w*k1.w
          + k2.x*k2.x + k2.y*k2.y + k2.z*k2.z + k2.w*k2.w;
    } else {
        d = e1.x*(e1.x - 2.f*k1.x) + e1.y*(e1.y - 2.f*k1.y)
          + e1.z*(e1.z - 2.f*k1.z) + e1.w*(e1.w - 2.f*k1.w)
          + e2.x*(e2.x - 2.f*k2.x) + e2.y*(e2.y - 2.f*k2.y)
          + e2.z*(e2.z - 2.f*k2.z) + e2.w*(e2.w - 2.f*k2.w);
    }
    #pragma unroll
    for (int s = 1; s <= 8; s <<= 1) d += __shfl_xor(d, s);

    const float ph  = __shfl(d, 0);
    const float pn  = __shfl(d, 16);
    const float p5  = __shfl(d, 32);
    const float sqk = __shfl(d, 48);

    // global argmin via EXACT u64 keys (8 chunk keys + S[512] key)
    u64 kk = ~0ULL;
    if (lane < 8)       kk = ((u64)mins[p*8 + lane] << 32) | (u64)mini16[p*8 + lane];
    else if (lane == 8) kk = ((u64)sortkey(p5) << 32) | 512ULL;
    #pragma unroll
    for (int s = 1; s <= 8; s <<= 1) {
        const u64 o = shflx64(kk, s);
        kk = (o < kk) ? o : kk;
    }
    const int mi = __shfl((int)(unsigned)(kk & 0xffffffffULL), 0);

    // pm: SELECT for special cases (bitwise equality), recompute otherwise
    float pm;
    if (mi == eh)      pm = ph;
    else if (mi == en) pm = pn;
    else if (mi == 512) pm = p5;
    else {
        const float4* mp = (const float4*)(emb + (size_t)mi*D_);
        const float4 m1 = mp[qm*2], m2 = mp[qm*2 + 1];
        float dm = m1.x*(m1.x - 2.f*k1.x) + m1.y*(m1.y - 2.f*k1.y)
                 + m1.z*(m1.z - 2.f*k1.z) + m1.w*(m1.w - 2.f*k1.w)
                 + m2.x*(m2.x - 2.f*k2.x) + m2.y*(m2.y - 2.f*k2.y)
                 + m2.z*(m2.z - 2.f*k2.z) + m2.w*(m2.w - 2.f*k2.w);
        #pragma unroll
        for (int s = 1; s <= 8; s <<= 1) dm += __shfl_xor(dm, s);
        pm = __shfl(dm, 0);
    }

    // key_hard: quad0 holds emb[eh] slices; kh = ks + (emb - ks) in fp32
    if (q == 0) {
        float4 o1, o2;
        o1.x = k1.x + (e1.x - k1.x); o1.y = k1.y + (e1.y - k1.y);
        o1.z = k1.z + (e1.z - k1.z); o1.w = k1.w + (e1.w - k1.w);
        o2.x = k2.x + (e2.x - k2.x); o2.y = k2.y + (e2.y - k2.y);
        o2.z = k2.z + (e2.z - k2.z); o2.w = k2.w + (e2.w - k2.w);
        ((float4*)(out + p*D_))[qm*2]     = o1;
        ((float4*)(out + p*D_))[qm*2 + 1] = o2;
    }

    if (lane == 0) {
        const float lh = 1.2f * (sqk + ph);
        const float ln = 1.2f * (sqk + pn);
        const float lm = 1.2f * (sqk + pm);
        out[O_LH + p] = lh - ln - ((pm < ph) ? lm : 0.f);
        out[O_LN + p] = ln - lh - ((pm < pn) ? lm : 0.f);
        energy[p] = 1.2f * (pn - ph);
    }
}

// ---------------------------------------------------------------------------
// kD1: per-256-position partial sums; LAST block (device atomic counter,
// zeroed by kFG each iteration) performs the final reduce + v-max.
// ---------------------------------------------------------------------------
__global__ __launch_bounds__(256) void kD1(const float* __restrict__ energy,
                                           const int* __restrict__ enci,
                                           double2* __restrict__ part,
                                           unsigned* __restrict__ cnt,
                                           float* __restrict__ out)
{
    __shared__ double sA[256], sB[256];
    __shared__ unsigned done;
    const int p = blockIdx.x * 256 + threadIdx.x;
    const float e = energy[p];
    double se = (double)e;
    double sl = 0.0;
    if ((p & (T_-1)) < T_-1) {
        const float ec = (enci[p+1] == enci[p]) ? (energy[p+1] - e) : 0.f;
        sl = (double)fmaxf(ec + (float)(1e-6/512.0), 0.f);
    }
    sA[threadIdx.x] = se; sB[threadIdx.x] = sl;
    __syncthreads();
    for (int s = 128; s >= 1; s >>= 1) {
        if (threadIdx.x < (unsigned)s) {
            sA[threadIdx.x] += sA[threadIdx.x+s];
            sB[threadIdx.x] += sB[threadIdx.x+s];
        }
        __syncthreads();
    }
    if (threadIdx.x == 0) {
        part[blockIdx.x] = make_double2(sA[0], sB[0]);
        __threadfence();
        done = atomicAdd(cnt, 1u);
    }
    __syncthreads();
    if (done != 255u) return;

    // ---- final phase, run by the last-finishing block ----
    __threadfence();
    double pvx, pvy;
    pvx = ((volatile double*)part)[2*threadIdx.x];
    pvy = ((volatile double*)part)[2*threadIdx.x + 1];
    __syncthreads();
    sA[threadIdx.x] = pvx; sB[threadIdx.x] = pvy;
    __syncthreads();
    for (int s = 128; s >= 1; s >>= 1) {
        if (threadIdx.x < (unsigned)s) {
            sA[threadIdx.x] += sA[threadIdx.x+s];
            sB[threadIdx.x] += sB[threadIdx.x+s];
        }
        __syncthreads();
    }
    if (threadIdx.x < 64) {
        int v = enci[(size_t)threadIdx.x*T_ + T_-1] - enci[(size_t)threadIdx.x*T_];
        #pragma unroll
        for (int m = 32; m >= 1; m >>= 1) {
            const int v2 = __shfl_xor(v, m);
            v = (v2 > v) ? v2 : v;
        }
        if (threadIdx.x == 0) {
            out[O_V]   = (float)v;
            out[O_EM]  = (float)(sA[0] / (double)P_);
            out[O_LED] = (float)(sB[0] / (double)(B_*(T_-1)));
        }
    }
}

// ---------------------------------------------------------------------------
extern "C" void kernel_launch(void* const* d_in, const int* in_sizes, int n_in,
                              void* d_out, int out_size, void* d_ws, size_t ws_size,
                              hipStream_t stream)
{
    const float* ks  = (const float*)d_in[0];
    const float* emb = (const float*)d_in[1];
    const unsigned char* mask = (const unsigned char*)d_in[2];

    float* out = (float*)d_out;
    char* w = (char*)d_ws;
    u64*      bits   = (u64*)     (w);                                    // 4 MB
    unsigned* mins   = (unsigned*)(w + (size_t) 8*1024*1024);             // 2 MB
    unsigned short* mini16 = (unsigned short*)(w + (size_t)10*1024*1024); // 1 MB
    int*      enci   = (int*)     (w + (size_t)11*1024*1024);             // 256 KB
    float*    energy = (float*)   (w + (size_t)11*1024*1024 + 256*1024);  // 256 KB
    float*    sq     = (float*)   (w + (size_t)11*1024*1024 + 512*1024);  // 4 KB
    double2*  part   = (double2*) (w + (size_t)11*1024*1024 + 516*1024);  // 4 KB
    unsigned* cnt    = (unsigned*)(w + (size_t)11*1024*1024 + 520*1024);  // 4 B
    unsigned short* ehi = (unsigned short*)(w + (size_t)11*1024*1024 + 640*1024); // 128 KB
    unsigned short* elo = (unsigned short*)(w + (size_t)11*1024*1024 + 768*1024); // 128 KB

    kFG<<<32,   64,  0, stream>>>(emb, ehi, elo, sq, cnt);
    kA <<<2048, 512, 0, stream>>>(ks, sq, ehi, elo, bits, mins, mini16);
    kB <<<B_,   64,  0, stream>>>(ks, emb, mask, bits, mins, mini16, enci, out);
    kC <<<P_/4, 256, 0, stream>>>(ks, emb, enci, mins, mini16, out, energy);
    kD1<<<256,  256, 0, stream>>>(energy, enci, part, cnt, out);
}

// Round 14
// 177.680 us; speedup vs baseline: 1.3002x; 1.3002x over previous
//
#include <hip/hip_runtime.h>
#include <cfloat>
#include <cstdint>

#define B_  64
#define T_  1024
#define D_  128
#define NE  512            // clip limit; emb has NE+1 = 513 rows
#define P_  (B_*T_)        // 65536 positions

// d_out flat offsets (float32), in reference return order
#define O_KH   0
#define O_ENC  (P_*D_)             // 8388608
#define O_V    (O_ENC + P_)        // 8454144
#define O_LH   (O_V + 1)           // 8454145
#define O_LN   (O_LH + P_)         // 8519681
#define O_EM   (O_LN + P_)         // 8585217
#define O_LED  (O_EM + 1)          // 8585218

typedef __attribute__((ext_vector_type(8))) short bf16x8;
typedef __attribute__((ext_vector_type(4))) float floatx4;
typedef unsigned long long u64;

// hi = truncate-to-bf16(x), lo = truncate-to-bf16(x - hi); pack 8 floats ->
// two uint4 (8 bf16 each, k-ascending little-endian)
__device__ __forceinline__ void pack8(const float4& a, const float4& b,
                                      uint4& h, uint4& l)
{
    float v[8] = {a.x,a.y,a.z,a.w,b.x,b.y,b.z,b.w};
    unsigned hw[4], lw[4];
    #pragma unroll
    for (int e = 0; e < 4; e++) {
        const unsigned ua = __float_as_uint(v[2*e]);
        const unsigned ub = __float_as_uint(v[2*e+1]);
        const float fa = __uint_as_float(ua & 0xffff0000u);
        const float fb = __uint_as_float(ub & 0xffff0000u);
        const unsigned da = __float_as_uint(v[2*e]   - fa);
        const unsigned db = __float_as_uint(v[2*e+1] - fb);
        hw[e] = (ub & 0xffff0000u) | (ua >> 16);
        lw[e] = (db & 0xffff0000u) | (da >> 16);
    }
    h = make_uint4(hw[0],hw[1],hw[2],hw[3]);
    l = make_uint4(lw[0],lw[1],lw[2],lw[3]);
}

__device__ __forceinline__ u64 shflx64(u64 v, int d)
{
    const int lo = __shfl_xor((int)(unsigned)(v & 0xffffffffULL), d);
    const int hi = __shfl_xor((int)(unsigned)(v >> 32), d);
    return ((u64)(unsigned)hi << 32) | (unsigned)lo;
}

// monotone float->uint map (strictly increasing) — EXACT, no quantization
__device__ __forceinline__ unsigned sortkey(float f)
{
    const unsigned b = __float_as_uint(f);
    return b ^ (unsigned)(((int)b >> 31) | (int)0x80000000);
}

// ---------------------------------------------------------------------------
// kFG: emb-only pre-conversion. Grid 32 x 64. Block 0 zeroes the kD
// completion counter (stream-ordered before kD1 -> safe).
// ---------------------------------------------------------------------------
__global__ __launch_bounds__(64) void kFG(const float* __restrict__ emb,
                                          unsigned short* __restrict__ ehi,
                                          unsigned short* __restrict__ elo,
                                          float* __restrict__ sq,
                                          unsigned* __restrict__ cnt)
{
    if (blockIdx.x == 0 && threadIdx.x == 0) *cnt = 0u;
    const int t = blockIdx.x * 64 + threadIdx.x;   // 0..2047
    const int n = t >> 2, kst = t & 3;
    const float4* src = (const float4*)(emb + (size_t)n * D_ + kst * 32);
    float ss = 0.f;
    #pragma unroll
    for (int g = 0; g < 4; g++) {
        const float4 a = src[2*g], b = src[2*g+1];
        ss += a.x*a.x + a.y*a.y + a.z*a.z + a.w*a.w
            + b.x*b.x + b.y*b.y + b.z*b.z + b.w*b.w;
        uint4 h, l;
        pack8(a, b, h, l);
        const int f = ((n >> 4) * 4 + kst) * 4 + g;
        *(uint4*)(ehi + (size_t)f*128 + (size_t)(n & 15)*8) = h;
        *(uint4*)(elo + (size_t)f*128 + (size_t)(n & 15)*8) = l;
    }
    ss += __shfl_xor(ss, 1);
    ss += __shfl_xor(ss, 2);
    if (kst == 0) sq[n] = ss;
}

// ---------------------------------------------------------------------------
// kA: transposed MFMA GEMM (M = n, N = p). R11 configuration (session best):
// one block = 512 threads = 8 waves = all 8 chunks of one 32-row p-half-tile;
// grid 2048; ks loaded+packed ONCE through LDS (XOR swizzle); single-buffered
// A-frags; in-block bit63. __launch_bounds__(512, 4) — R12's (512,6) forced
// the allocator to ~85 regs -> scratch spills (FETCH 17.5->70 MB, WRITE
// 11->140 MB, kA 42->92 us). The working set needs the ~96-112 regs that
// (512,4) allows; do NOT raise the waves/EU bound.
// NO cross-block fencing (R6: 2048 device-scope fences = 16x regression).
// pack8/MFMA value+order identical throughout -> bit-identical outputs.
// ---------------------------------------------------------------------------
__global__ __launch_bounds__(512, 4) void kA(const float* __restrict__ ks,
                                          const float* __restrict__ sq,
                                          const unsigned short* __restrict__ ehi,
                                          const unsigned short* __restrict__ elo,
                                          u64* __restrict__ bits,
                                          unsigned* __restrict__ mins,
                                          unsigned short* __restrict__ mini16)
{
    __shared__ unsigned short Bh[32*128];   // 8 KB, [row][col] bf16, swizzled
    __shared__ unsigned short Bl[32*128];   // 8 KB
    __shared__ float S00x[8][2][16];        // 1 KB: S[0][0] per (wave, j, m)

    const int tid  = threadIdx.x;
    const int lane = tid & 63;
    const int wv   = tid >> 6;                // 0..7
    const int m    = lane & 15;               // p within 16-tile
    const int q    = lane >> 4;               // quad
    const int bid  = blockIdx.x;
    const int h    = bid >> 10;               // p-half 0/1
    const int pt   = bid & 1023;
    const int p0   = pt * 64 + h * 32;        // first p of this block
    const int ch   = wv;                      // chunk 0..7
    const int nb   = ch * 64;

    // ---- cooperative stage: 512 threads x 32 B -> 16 KB bf16 hi/lo ----
    {
        const int srow = tid >> 4;            // 0..31
        const int scg  = tid & 15;            // 8-col group
        const float4* sp = (const float4*)(ks + ((size_t)p0 + srow)*D_ + scg*8);
        uint4 hh, ll;
        pack8(sp[0], sp[1], hh, ll);
        const int cb = (srow*256 + scg*16) ^ ((srow & 7) << 4);
        *(uint4*)((char*)Bh + cb) = hh;
        *(uint4*)((char*)Bl + cb) = ll;
    }
    __syncthreads();

    floatx4 acc[4][2];
    #pragma unroll
    for (int i = 0; i < 4; i++)
        #pragma unroll
        for (int j = 0; j < 2; j++)
            #pragma unroll
            for (int r = 0; r < 4; r++) acc[i][j][r] = 0.f;

    bf16x8 ah[4], al[4], bh[2], bl[2];

    auto loadA = [&](int kst) {
        #pragma unroll
        for (int i = 0; i < 4; i++) {
            const int off = (((ch*4 + i) * 4 + kst) * 4 + q) * 128 + m*8;
            ah[i] = *(const bf16x8*)(ehi + off);
            al[i] = *(const bf16x8*)(elo + off);
        }
    };
    auto loadB = [&](int kst) {
        #pragma unroll
        for (int j = 0; j < 2; j++) {
            const int row = j*16 + m;
            const int cb = (row*256 + kst*64 + q*16) ^ ((row & 7) << 4);
            bh[j] = *(const bf16x8*)((const char*)Bh + cb);
            bl[j] = *(const bf16x8*)((const char*)Bl + cb);
        }
    };
    auto mfma3 = [&]() {
        __builtin_amdgcn_s_setprio(1);
        #pragma unroll
        for (int i = 0; i < 4; i++)
            #pragma unroll
            for (int j = 0; j < 2; j++)
                acc[i][j] = __builtin_amdgcn_mfma_f32_16x16x32_bf16(ah[i], bh[j], acc[i][j], 0, 0, 0);
        #pragma unroll
        for (int i = 0; i < 4; i++)
            #pragma unroll
            for (int j = 0; j < 2; j++)
                acc[i][j] = __builtin_amdgcn_mfma_f32_16x16x32_bf16(ah[i], bl[j], acc[i][j], 0, 0, 0);
        #pragma unroll
        for (int i = 0; i < 4; i++)
            #pragma unroll
            for (int j = 0; j < 2; j++)
                acc[i][j] = __builtin_amdgcn_mfma_f32_16x16x32_bf16(al[i], bh[j], acc[i][j], 0, 0, 0);
        __builtin_amdgcn_s_setprio(0);
    };

    #pragma unroll
    for (int kst = 0; kst < 3; kst++) {
        loadA(kst);
        loadB(kst);
        mfma3();
    }
    loadA(3);
    loadB(3);
    // prefetch epilogue sq under the last MFMA cluster
    float sa[4][4];
    #pragma unroll
    for (int i = 0; i < 4; i++) {
        const float4 s4 = *(const float4*)(sq + nb + i*16 + q*4);
        sa[i][0]=s4.x; sa[i][1]=s4.y; sa[i][2]=s4.z; sa[i][3]=s4.w;
    }
    mfma3();

    // ---- publish S[0][0] per (wave, j, m) for the in-block bit63 patch.
    // Same expression the main loop computes on the q==0 lane -> bitwise
    // identical to the value previously stored in sfirst. ----
    if (q == 0) {
        S00x[wv][0][m] = fmaf(-2.f, acc[0][0][0], sa[0][0]);
        S00x[wv][1][m] = fmaf(-2.f, acc[0][1][0], sa[0][0]);
    }
    __syncthreads();
    const int wnx = (wv < 7) ? wv + 1 : 7;           // clamped (unused at ch==7)

    // ---- epilogue (register-local; bit63 fully resolved here) ----
    #pragma unroll
    for (int j = 0; j < 2; j++) {
        float S[4][4];
        #pragma unroll
        for (int i = 0; i < 4; i++)
            #pragma unroll
            for (int r = 0; r < 4; r++)
                S[i][r] = fmaf(-2.f, acc[i][j][r], sa[i][r]);

        // neighbor S at quad/tile boundaries
        float nq[4], ni[4];
        #pragma unroll
        for (int i = 0; i < 4; i++) nq[i] = __shfl_down(S[i][0], 16);
        #pragma unroll
        for (int i = 0; i < 3; i++) ni[i] = __shfl(S[i+1][0], m);
        ni[3] = 0.f;

        u64 w = 0;
        #pragma unroll
        for (int i = 0; i < 4; i++) {
            #pragma unroll
            for (int r = 0; r < 3; r++)
                w |= (u64)(S[i][r] <= S[i][r+1]) << (16*i + 4*q + r);
            if (!(i == 3 && q == 3)) {
                const float nxt = (q < 3) ? nq[i] : ni[i];
                w |= (u64)(S[i][3] <= nxt) << (16*i + 4*q + 3);
            }
        }
        // bit63: chunk-boundary "stay" bit. ch==7 -> n=511 clip (always
        // stay); else compare this chunk's last S with next chunk's first S
        // (value read from LDS; bitwise equal to the old sfirst round-trip).
        if (q == 3) {
            const u64 b63 = (ch == 7) ? 1ULL
                          : (u64)(S[3][3] <= S00x[wnx][j][m]);
            w |= b63 << 63;
        }
        w |= shflx64(w, 16);
        w |= shflx64(w, 32);

        // chunk argmin, EXACT (first-index tie-break)
        float mv = S[0][0]; int mi_ = nb + q*4;
        #pragma unroll
        for (int i = 0; i < 4; i++)
            #pragma unroll
            for (int r = 0; r < 4; r++) {
                if (i == 0 && r == 0) continue;
                const int nid = nb + 16*i + 4*q + r;
                if (S[i][r] < mv) { mv = S[i][r]; mi_ = nid; }
            }
        #pragma unroll
        for (int d = 16; d <= 32; d <<= 1) {
            const float v2 = __shfl_xor(mv, d);
            const int   i2 = __shfl_xor(mi_, d);
            if (v2 < mv || (v2 == mv && i2 < mi_)) { mv = v2; mi_ = i2; }
        }

        const size_t pg = (size_t)(p0 + j*16 + m);
        if (q == 0) {
            bits  [pg*8 + ch] = w;
            mins  [pg*8 + ch] = sortkey(mv);
            mini16[pg*8 + ch] = (unsigned short)mi_;
        }
    }
}

// ---------------------------------------------------------------------------
// kB: one wave per b. Windows carry ONLY the 8 bits words (64 B/t; bit63
// arrives pre-resolved from kA). Scalarized named registers (R10: struct
// buffers were demoted to scratch), 4 rotating windows = 3-deep prefetch,
// loads issued before ind0. Same scan arithmetic, window order 0..15 ->
// bit-identical outputs.
// ---------------------------------------------------------------------------
#define KB_DECL(S) \
    u64 W0##S,W1##S,W2##S,W3##S,W4##S,W5##S,W6##S,W7##S;

#define KB_LOAD(S, T0)                                                      \
    {                                                                       \
        const int t_ = (T0) + lane;                                         \
        if (t_ < T_) {                                                      \
            const ulonglong2* bp_ = (const ulonglong2*)(bits + (p0 + t_)*8);\
            const ulonglong2 b01_ = bp_[0], b23_ = bp_[1];                  \
            const ulonglong2 b45_ = bp_[2], b67_ = bp_[3];                  \
            W0##S=b01_.x; W1##S=b01_.y; W2##S=b23_.x; W3##S=b23_.y;         \
            W4##S=b45_.x; W5##S=b45_.y; W6##S=b67_.x; W7##S=b67_.y;         \
        } else {                                                            \
            W0##S=~0ULL; W1##S=~0ULL; W2##S=~0ULL; W3##S=~0ULL;             \
            W4##S=~0ULL; W5##S=~0ULL; W6##S=~0ULL; W7##S=~0ULL;             \
        }                                                                   \
    }

#define KB_SCAN(S, T0)                                                      \
    {                                                                       \
        const int wsel_ = cur >> 6;                                         \
        const int off0_ = cur & 63;                                         \
        u64 a_ = W0##S;                                                     \
        a_ = (wsel_ == 1) ? W1##S : a_;                                     \
        a_ = (wsel_ == 2) ? W2##S : a_;                                     \
        a_ = (wsel_ == 3) ? W3##S : a_;                                     \
        a_ = (wsel_ == 4) ? W4##S : a_;                                     \
        a_ = (wsel_ == 5) ? W5##S : a_;                                     \
        a_ = (wsel_ == 6) ? W6##S : a_;                                     \
        a_ = (wsel_ == 7) ? W7##S : a_;                                     \
        u64 bn_ = ~0ULL;                                                    \
        bn_ = (wsel_ == 0) ? W1##S : bn_;                                   \
        bn_ = (wsel_ == 1) ? W2##S : bn_;                                   \
        bn_ = (wsel_ == 2) ? W3##S : bn_;                                   \
        bn_ = (wsel_ == 3) ? W4##S : bn_;                                   \
        bn_ = (wsel_ == 4) ? W5##S : bn_;                                   \
        bn_ = (wsel_ == 5) ? W6##S : bn_;                                   \
        bn_ = (wsel_ == 6) ? W7##S : bn_;                                   \
        const u64 u_ = (off0_ == 0) ? a_                                    \
                     : ((a_ >> off0_) | (bn_ << (64 - off0_)));             \
        const unsigned ulo_ = (unsigned)u_;                                 \
        const unsigned uhi_ = (unsigned)(u_ >> 32);                         \
        int doff_ = 0;                                                      \
        int myenc_ = cur;                                                   \
        _Pragma("unroll")                                                   \
        for (int j_ = 0; j_ < 64; j_++) {                                   \
            const unsigned slo_ = (unsigned)__builtin_amdgcn_readlane((int)ulo_, j_); \
            const unsigned shi_ = (unsigned)__builtin_amdgcn_readlane((int)uhi_, j_); \
            const u64 word_ = ((u64)shi_ << 32) | slo_;                     \
            const int bit_ = (int)((word_ >> doff_) & 1ULL);                \
            doff_ += 1 - bit_;                                              \
            if (lane == j_) myenc_ = cur + doff_;                           \
        }                                                                   \
        cur += doff_;                                                       \
        const int t_ = (T0) + lane;                                         \
        if (t_ < T_) {                                                      \
            enci[p0 + t_] = myenc_;                                         \
            out[O_ENC + p0 + t_] = (float)myenc_;                           \
        }                                                                   \
    }

__global__ __launch_bounds__(64) void kB(const float* __restrict__ ks,
                                         const float* __restrict__ emb,
                                         const unsigned char* __restrict__ mask,
                                         const u64* __restrict__ bits,
                                         const unsigned* __restrict__ mins,
                                         const unsigned short* __restrict__ mini16,
                                         int* __restrict__ enci,
                                         float* __restrict__ out)
{
    const int b    = blockIdx.x;
    const int lane = threadIdx.x;
    const size_t p0 = (size_t)b * T_;

    KB_DECL(A)
    KB_DECL(B)
    KB_DECL(C)
    KB_DECL(D)

    // windows 0..3 in flight BEFORE ind0 (independent of it) — ind0's
    // emb/ks loads + reduce cover their cross-XCD latency.
    KB_LOAD(A, 1)
    KB_LOAD(B, 65)
    KB_LOAD(C, 129)
    KB_LOAD(D, 193)

    // ind0: S[512] exact + 8 exact chunk keys
    const float2 e = ((const float2*)(emb + (size_t)512*D_))[lane];
    const float2 k = ((const float2*)(ks  + p0*D_))[lane];
    float s5 = e.x*(e.x - 2.f*k.x) + e.y*(e.y - 2.f*k.y);
    #pragma unroll
    for (int m = 32; m >= 1; m >>= 1) s5 += __shfl_xor(s5, m);

    u64 kk = ~0ULL;
    if (lane < 8)       kk = ((u64)mins[p0*8 + lane] << 32) | (u64)mini16[p0*8 + lane];
    else if (lane == 8) kk = ((u64)sortkey(s5) << 32) | 512ULL;
    #pragma unroll
    for (int d = 1; d <= 8; d <<= 1) {
        const u64 o = shflx64(kk, d);
        kk = (o < kk) ? o : kk;
    }
    const int mi = __shfl((int)(unsigned)(kk & 0xffffffffULL), 0);
    int cur = (mi < NE) ? mi : NE - 1;
    if (mask[b]) cur = 0;
    if (lane == 0) { enci[p0] = cur; out[O_ENC + p0] = (float)cur; }

    #pragma unroll 1
    for (int wp = 0; wp < 16; wp += 4) {
        const int t0 = 1 + wp*64;
        KB_SCAN(A, t0)
        if (wp + 4 < 16) KB_LOAD(A, t0 + 256)
        KB_SCAN(B, t0 + 64)
        if (wp + 5 < 16) KB_LOAD(B, t0 + 320)
        KB_SCAN(C, t0 + 128)
        if (wp + 6 < 16) KB_LOAD(C, t0 + 384)
        KB_SCAN(D, t0 + 192)
        if (wp + 7 < 16) KB_LOAD(D, t0 + 448)
    }
}

// ---------------------------------------------------------------------------
// kC: one wave per position, quad-split. Quad q computes one dot:
// q0: S[eh], q1: S[en], q2: S[512], q3: ||ks||^2. Global argmin via EXACT
// u64 keys. pm is SELECTED (pm=ph / pn / p5) when mi hits a special case —
// bitwise-guaranteed equality regardless of codegen/contraction. Recompute
// only for genuinely distinct mi (real gap -> rounding-safe).
// ---------------------------------------------------------------------------
__global__ __launch_bounds__(256) void kC(const float* __restrict__ ks,
                                          const float* __restrict__ emb,
                                          const int* __restrict__ enci,
                                          const unsigned* __restrict__ mins,
                                          const unsigned short* __restrict__ mini16,
                                          float* __restrict__ out,
                                          float* __restrict__ energy)
{
    const int lane = threadIdx.x & 63;
    const size_t p = (size_t)blockIdx.x * 4 + (threadIdx.x >> 6);
    const int q  = lane >> 4;
    const int qm = lane & 15;

    const int eh = enci[p];
    const int en = (eh + 1 < NE) ? eh + 1 : NE - 1;
    const int row = (q == 0) ? eh : ((q == 1) ? en : 512);

    const float4* ksp = (const float4*)(ks + p*D_);
    const float4 k1 = ksp[qm*2], k2 = ksp[qm*2 + 1];
    const float4* ep = (const float4*)(emb + (size_t)row*D_);
    const float4 e1 = ep[qm*2], e2 = ep[qm*2 + 1];

    float d;
    if (q == 3) {
        d = k1.x*k1.x + k1.y*k1.y + k1.z*k1.z + k1.w*k1.w
          + k2.x*k2.x + k2.y*k2.y + k2.z*k2.z + k2.w*k2.w;
    } else {
        d = e1.x*(e1.x - 2.f*k1.x) + e1.y*(e1.y - 2.f*k1.y)
          + e1.z*(e1.z - 2.f*k1.z) + e1.w*(e1.w - 2.f*k1.w)
          + e2.x*(e2.x - 2.f*k2.x) + e2.y*(e2.y - 2.f*k2.y)
          + e2.z*(e2.z - 2.f*k2.z) + e2.w*(e2.w - 2.f*k2.w);
    }
    #pragma unroll
    for (int s = 1; s <= 8; s <<= 1) d += __shfl_xor(d, s);

    const float ph  = __shfl(d, 0);
    const float pn  = __shfl(d, 16);
    const float p5  = __shfl(d, 32);
    const float sqk = __shfl(d, 48);

    // global argmin via EXACT u64 keys (8 chunk keys + S[512] key)
    u64 kk = ~0ULL;
    if (lane < 8)       kk = ((u64)mins[p*8 + lane] << 32) | (u64)mini16[p*8 + lane];
    else if (lane == 8) kk = ((u64)sortkey(p5) << 32) | 512ULL;
    #pragma unroll
    for (int s = 1; s <= 8; s <<= 1) {
        const u64 o = shflx64(kk, s);
        kk = (o < kk) ? o : kk;
    }
    const int mi = __shfl((int)(unsigned)(kk & 0xffffffffULL), 0);

    // pm: SELECT for special cases (bitwise equality), recompute otherwise
    float pm;
    if (mi == eh)      pm = ph;
    else if (mi == en) pm = pn;
    else if (mi == 512) pm = p5;
    else {
        const float4* mp = (const float4*)(emb + (size_t)mi*D_);
        const float4 m1 = mp[qm*2], m2 = mp[qm*2 + 1];
        float dm = m1.x*(m1.x - 2.f*k1.x) + m1.y*(m1.y - 2.f*k1.y)
                 + m1.z*(m1.z - 2.f*k1.z) + m1.w*(m1.w - 2.f*k1.w)
                 + m2.x*(m2.x - 2.f*k2.x) + m2.y*(m2.y - 2.f*k2.y)
                 + m2.z*(m2.z - 2.f*k2.z) + m2.w*(m2.w - 2.f*k2.w);
        #pragma unroll
        for (int s = 1; s <= 8; s <<= 1) dm += __shfl_xor(dm, s);
        pm = __shfl(dm, 0);
    }

    // key_hard: quad0 holds emb[eh] slices; kh = ks + (emb - ks) in fp32
    if (q == 0) {
        float4 o1, o2;
        o1.x = k1.x + (e1.x - k1.x); o1.y = k1.y + (e1.y - k1.y);
        o1.z = k1.z + (e1.z - k1.z); o1.w = k1.w + (e1.w - k1.w);
        o2.x = k2.x + (e2.x - k2.x); o2.y = k2.y + (e2.y - k2.y);
        o2.z = k2.z + (e2.z - k2.z); o2.w = k2.w + (e2.w - k2.w);
        ((float4*)(out + p*D_))[qm*2]     = o1;
        ((float4*)(out + p*D_))[qm*2 + 1] = o2;
    }

    if (lane == 0) {
        const float lh = 1.2f * (sqk + ph);
        const float ln = 1.2f * (sqk + pn);
        const float lm = 1.2f * (sqk + pm);
        out[O_LH + p] = lh - ln - ((pm < ph) ? lm : 0.f);
        out[O_LN + p] = ln - lh - ((pm < pn) ? lm : 0.f);
        energy[p] = 1.2f * (pn - ph);
    }
}

// ---------------------------------------------------------------------------
// kD1: per-256-position partial sums; LAST block (device atomic counter,
// zeroed by kFG each iteration) performs the final reduce + v-max.
// ---------------------------------------------------------------------------
__global__ __launch_bounds__(256) void kD1(const float* __restrict__ energy,
                                           const int* __restrict__ enci,
                                           double2* __restrict__ part,
                                           unsigned* __restrict__ cnt,
                                           float* __restrict__ out)
{
    __shared__ double sA[256], sB[256];
    __shared__ unsigned done;
    const int p = blockIdx.x * 256 + threadIdx.x;
    const float e = energy[p];
    double se = (double)e;
    double sl = 0.0;
    if ((p & (T_-1)) < T_-1) {
        const float ec = (enci[p+1] == enci[p]) ? (energy[p+1] - e) : 0.f;
        sl = (double)fmaxf(ec + (float)(1e-6/512.0), 0.f);
    }
    sA[threadIdx.x] = se; sB[threadIdx.x] = sl;
    __syncthreads();
    for (int s = 128; s >= 1; s >>= 1) {
        if (threadIdx.x < (unsigned)s) {
            sA[threadIdx.x] += sA[threadIdx.x+s];
            sB[threadIdx.x] += sB[threadIdx.x+s];
        }
        __syncthreads();
    }
    if (threadIdx.x == 0) {
        part[blockIdx.x] = make_double2(sA[0], sB[0]);
        __threadfence();
        done = atomicAdd(cnt, 1u);
    }
    __syncthreads();
    if (done != 255u) return;

    // ---- final phase, run by the last-finishing block ----
    __threadfence();
    double pvx, pvy;
    pvx = ((volatile double*)part)[2*threadIdx.x];
    pvy = ((volatile double*)part)[2*threadIdx.x + 1];
    __syncthreads();
    sA[threadIdx.x] = pvx; sB[threadIdx.x] = pvy;
    __syncthreads();
    for (int s = 128; s >= 1; s >>= 1) {
        if (threadIdx.x < (unsigned)s) {
            sA[threadIdx.x] += sA[threadIdx.x+s];
            sB[threadIdx.x] += sB[threadIdx.x+s];
        }
        __syncthreads();
    }
    if (threadIdx.x < 64) {
        int v = enci[(size_t)threadIdx.x*T_ + T_-1] - enci[(size_t)threadIdx.x*T_];
        #pragma unroll
        for (int m = 32; m >= 1; m >>= 1) {
            const int v2 = __shfl_xor(v, m);
            v = (v2 > v) ? v2 : v;
        }
        if (threadIdx.x == 0) {
            out[O_V]   = (float)v;
            out[O_EM]  = (float)(sA[0] / (double)P_);
            out[O_LED] = (float)(sB[0] / (double)(B_*(T_-1)));
        }
    }
}

// ---------------------------------------------------------------------------
extern "C" void kernel_launch(void* const* d_in, const int* in_sizes, int n_in,
                              void* d_out, int out_size, void* d_ws, size_t ws_size,
                              hipStream_t stream)
{
    const float* ks  = (const float*)d_in[0];
    const float* emb = (const float*)d_in[1];
    const unsigned char* mask = (const unsigned char*)d_in[2];

    float* out = (float*)d_out;
    char* w = (char*)d_ws;
    u64*      bits   = (u64*)     (w);                                    // 4 MB
    unsigned* mins   = (unsigned*)(w + (size_t) 8*1024*1024);             // 2 MB
    unsigned short* mini16 = (unsigned short*)(w + (size_t)10*1024*1024); // 1 MB
    int*      enci   = (int*)     (w + (size_t)11*1024*1024);             // 256 KB
    float*    energy = (float*)   (w + (size_t)11*1024*1024 + 256*1024);  // 256 KB
    float*    sq     = (float*)   (w + (size_t)11*1024*1024 + 512*1024);  // 4 KB
    double2*  part   = (double2*) (w + (size_t)11*1024*1024 + 516*1024);  // 4 KB
    unsigned* cnt    = (unsigned*)(w + (size_t)11*1024*1024 + 520*1024);  // 4 B
    unsigned short* ehi = (unsigned short*)(w + (size_t)11*1024*1024 + 640*1024); // 128 KB
    unsigned short* elo = (unsigned short*)(w + (size_t)11*1024*1024 + 768*1024); // 128 KB

    kFG<<<32,   64,  0, stream>>>(emb, ehi, elo, sq, cnt);
    kA <<<2048, 512, 0, stream>>>(ks, sq, ehi, elo, bits, mins, mini16);
    kB <<<B_,   64,  0, stream>>>(ks, emb, mask, bits, mins, mini16, enci, out);
    kC <<<P_/4, 256, 0, stream>>>(ks, emb, enci, mins, mini16, out, energy);
    kD1<<<256,  256, 0, stream>>>(energy, enci, part, cnt, out);
}